// Round 1
// baseline (361.837 us; speedup 1.0000x reference)
//
#include <hip/hip_runtime.h>

// B=4, S=2048, E=1024, H=16, D=64.  M = B*S = 8192.
// Pipeline: cvt(qkv,w_in,w_out fp32->bf16) -> gemm1 (x1 = qkv@W_in^T + b_in, bf16)
//           -> flash attention (bf16, f32 accum) -> gemm2 (f32 out = attn@W_out^T + b_out)
// 1/sqrt(D) folded into W_q rows / b_q (first 1024 output features of in_proj).
// Workspace layout (75,497,472 bytes total):
//   [0, 16MB)        qkv_bf16   (reused as attn_out after gemm1 consumes it)
//   [16MB, +6MB)     w_in bf16
//   [+2MB)           w_out bf16
//   [25165824, +48MB) x1 bf16 [8192][3072]

typedef __attribute__((ext_vector_type(8))) short s16x8;
typedef __attribute__((ext_vector_type(8))) __bf16 bf16x8;
typedef __attribute__((ext_vector_type(4))) float f32x4;
typedef __attribute__((ext_vector_type(4))) unsigned short u16x4;

__device__ __forceinline__ unsigned short f2bf(float f) {
  unsigned int u = __builtin_bit_cast(unsigned int, f);
  u += 0x7fffu + ((u >> 16) & 1u);
  return (unsigned short)(u >> 16);
}

__device__ __forceinline__ f32x4 mfma16(s16x8 a, s16x8 b, f32x4 c) {
  return __builtin_amdgcn_mfma_f32_16x16x32_bf16(
      __builtin_bit_cast(bf16x8, a), __builtin_bit_cast(bf16x8, b), c, 0, 0, 0);
}

#define GLL16(gp, lp) __builtin_amdgcn_global_load_lds(                       \
    (const __attribute__((address_space(1))) void*)(gp),                      \
    (__attribute__((address_space(3))) void*)(lp), 16, 0, 0)

// ---------------- fp32 -> bf16 conversion (first scale_n elems *0.125) -----
__global__ void cvt_f32_bf16(const float* __restrict__ in,
                             unsigned short* __restrict__ out,
                             int n, int scale_n) {
  int idx = (blockIdx.x * 256 + threadIdx.x) * 4;
  int stride = gridDim.x * 256 * 4;
  for (int i = idx; i < n; i += stride) {
    const float4 v = *reinterpret_cast<const float4*>(in + i);
    const float sc = (i < scale_n) ? 0.125f : 1.0f;
    u16x4 r;
    r.x = f2bf(v.x * sc); r.y = f2bf(v.y * sc);
    r.z = f2bf(v.z * sc); r.w = f2bf(v.w * sc);
    *reinterpret_cast<u16x4*>(out + i) = r;
  }
}

// ---------------- bf16 NT GEMM: C[M,N] = A[M,K] * B[N,K]^T + bias ----------
// 128x128 tile, BK=64, 256 threads (2x2 waves of 64x64), m97 structure.
template <bool OUT_BF16>
__global__ __launch_bounds__(256, 2) void gemm_nt(
    const unsigned short* __restrict__ A, const unsigned short* __restrict__ B,
    const float* __restrict__ bias, void* __restrict__ Cout,
    int M, int N, int K, int qscale_cols) {
  __shared__ __align__(16) unsigned short As[128 * 64];
  __shared__ __align__(16) unsigned short Bs[128 * 64];
  const int tid = threadIdx.x;
  const int lane = tid & 63, w = tid >> 6;
  const int l15 = lane & 15, l4 = lane >> 4;
  const int wr = w >> 1, wc = w & 1;
  const int bm = blockIdx.y * 128, bn = blockIdx.x * 128;

  f32x4 acc[4][4];
#pragma unroll
  for (int i = 0; i < 4; ++i)
#pragma unroll
    for (int j = 0; j < 4; ++j) acc[i][j] = (f32x4){0.f, 0.f, 0.f, 0.f};

  for (int kt = 0; kt < K; kt += 64) {
#pragma unroll
    for (int j = 0; j < 4; ++j) {
      const int gb = (j * 4 + w) * 64;           // wave-uniform
      const int g = gb + lane;
      const int row = g >> 3, seg = g & 7;
      GLL16(A + (size_t)(bm + row) * K + kt + seg * 8, As + gb * 8);
      GLL16(B + (size_t)(bn + row) * K + kt + seg * 8, Bs + gb * 8);
    }
    __syncthreads();
#pragma unroll
    for (int kk = 0; kk < 2; ++kk) {
      s16x8 a[4], b[4];
#pragma unroll
      for (int mi = 0; mi < 4; ++mi)
        a[mi] = *reinterpret_cast<const s16x8*>(
            As + (wr * 64 + mi * 16 + l15) * 64 + kk * 32 + l4 * 8);
#pragma unroll
      for (int ni = 0; ni < 4; ++ni)
        b[ni] = *reinterpret_cast<const s16x8*>(
            Bs + (wc * 64 + ni * 16 + l15) * 64 + kk * 32 + l4 * 8);
#pragma unroll
      for (int mi = 0; mi < 4; ++mi)
#pragma unroll
        for (int ni = 0; ni < 4; ++ni)
          acc[mi][ni] = mfma16(a[mi], b[ni], acc[mi][ni]);
    }
    __syncthreads();
  }
#pragma unroll
  for (int mi = 0; mi < 4; ++mi) {
#pragma unroll
    for (int ni = 0; ni < 4; ++ni) {
      const int col = bn + wc * 64 + ni * 16 + l15;
      const float bsc = (col < qscale_cols) ? 0.125f : 1.0f;
      const float bv = bias[col] * bsc;
#pragma unroll
      for (int r = 0; r < 4; ++r) {
        const int row = bm + wr * 64 + mi * 16 + l4 * 4 + r;
        const float val = acc[mi][ni][r] + bv;
        if (OUT_BF16)
          ((unsigned short*)Cout)[(size_t)row * N + col] = f2bf(val);
        else
          ((float*)Cout)[(size_t)row * N + col] = val;
      }
    }
  }
}

// ---------------- flash attention ------------------------------------------
// grid (16 q-tiles, 64 b*h); block 256 = 4 waves, each wave owns 32 q rows.
// X1 row layout: [Q(1024, pre-scaled by 1/8) | K(1024) | V(1024)]
__global__ __launch_bounds__(256, 2) void attn_fwd(
    const unsigned short* __restrict__ X1, unsigned short* __restrict__ O) {
  __shared__ __align__(16) unsigned short Ks[64 * 64];
  __shared__ __align__(16) unsigned short Vt[64 * 72];       // [d][key], pad 72
  __shared__ __align__(16) unsigned short Ps[4][32 * 72];    // per-wave P

  const int qt = blockIdx.x;   // 0..15
  const int bh = blockIdx.y;   // 0..63
  const int b = bh >> 4, h = bh & 15;
  const int tid = threadIdx.x;
  const int lane = tid & 63, w = tid >> 6;
  const int l15 = lane & 15, l4 = lane >> 4;

  const unsigned short* Qp = X1 + (size_t)b * 2048 * 3072 + h * 64;
  const unsigned short* Kp = Qp + 1024;
  const unsigned short* Vp = Qp + 2048;
  const int q0 = qt * 128 + w * 32;

  s16x8 qf[2][2];
#pragma unroll
  for (int mi = 0; mi < 2; ++mi)
#pragma unroll
    for (int kk = 0; kk < 2; ++kk)
      qf[mi][kk] = *reinterpret_cast<const s16x8*>(
          Qp + (size_t)(q0 + mi * 16 + l15) * 3072 + kk * 32 + l4 * 8);

  f32x4 oacc[2][4];
  float m_r[2][4], l_r[2][4];
#pragma unroll
  for (int mi = 0; mi < 2; ++mi) {
#pragma unroll
    for (int nd = 0; nd < 4; ++nd) oacc[mi][nd] = (f32x4){0.f, 0.f, 0.f, 0.f};
#pragma unroll
    for (int r = 0; r < 4; ++r) { m_r[mi][r] = -1e30f; l_r[mi][r] = 0.f; }
  }
  unsigned short* Pw = &Ps[w][0];

  for (int kt = 0; kt < 2048; kt += 64) {
    // stage K tile (64x64) via global_load_lds (linear dest)
#pragma unroll
    for (int j = 0; j < 2; ++j) {
      const int gb = (j * 4 + w) * 64;
      const int g = gb + lane;
      const int row = g >> 3, seg = g & 7;
      GLL16(Kp + (size_t)(kt + row) * 3072 + seg * 8, Ks + gb * 8);
    }
    // stage V transposed: Vt[d][key], one row per lane -> conflict-light writes
#pragma unroll
    for (int j = 0; j < 2; ++j) {
      const int seg = w + 4 * j;
      s16x8 v = *reinterpret_cast<const s16x8*>(
          Vp + (size_t)(kt + lane) * 3072 + seg * 8);
#pragma unroll
      for (int e = 0; e < 8; ++e)
        Vt[(seg * 8 + e) * 72 + lane] = (unsigned short)v[e];
    }
    __syncthreads();

    // S = Q' K^T   (scale pre-folded into Q)
    f32x4 s[2][4];
#pragma unroll
    for (int mi = 0; mi < 2; ++mi)
#pragma unroll
      for (int ni = 0; ni < 4; ++ni) s[mi][ni] = (f32x4){0.f, 0.f, 0.f, 0.f};
#pragma unroll
    for (int kk = 0; kk < 2; ++kk) {
      s16x8 kb[4];
#pragma unroll
      for (int ni = 0; ni < 4; ++ni)
        kb[ni] = *reinterpret_cast<const s16x8*>(
            Ks + (ni * 16 + l15) * 64 + kk * 32 + l4 * 8);
#pragma unroll
      for (int mi = 0; mi < 2; ++mi)
#pragma unroll
        for (int ni = 0; ni < 4; ++ni)
          s[mi][ni] = mfma16(qf[mi][kk], kb[ni], s[mi][ni]);
    }

    // online softmax (rows q = l4*4+r within 16-row frag; cols = keys = l15)
    float mx[2][4];
#pragma unroll
    for (int mi = 0; mi < 2; ++mi)
#pragma unroll
      for (int r = 0; r < 4; ++r)
        mx[mi][r] = fmaxf(fmaxf(s[mi][0][r], s[mi][1][r]),
                          fmaxf(s[mi][2][r], s[mi][3][r]));
#pragma unroll
    for (int off = 1; off <= 8; off <<= 1)
#pragma unroll
      for (int mi = 0; mi < 2; ++mi)
#pragma unroll
        for (int r = 0; r < 4; ++r)
          mx[mi][r] = fmaxf(mx[mi][r], __shfl_xor(mx[mi][r], off));

    float alpha[2][4];
#pragma unroll
    for (int mi = 0; mi < 2; ++mi)
#pragma unroll
      for (int r = 0; r < 4; ++r) {
        const float mn = fmaxf(m_r[mi][r], mx[mi][r]);
        alpha[mi][r] = __expf(m_r[mi][r] - mn);
        m_r[mi][r] = mn;
      }
    float rs[2][4];
#pragma unroll
    for (int mi = 0; mi < 2; ++mi)
#pragma unroll
      for (int r = 0; r < 4; ++r) rs[mi][r] = 0.f;
#pragma unroll
    for (int mi = 0; mi < 2; ++mi)
#pragma unroll
      for (int ni = 0; ni < 4; ++ni)
#pragma unroll
        for (int r = 0; r < 4; ++r) {
          const float p = __expf(s[mi][ni][r] - m_r[mi][r]);
          s[mi][ni][r] = p;
          rs[mi][r] += p;
        }
#pragma unroll
    for (int off = 1; off <= 8; off <<= 1)
#pragma unroll
      for (int mi = 0; mi < 2; ++mi)
#pragma unroll
        for (int r = 0; r < 4; ++r)
          rs[mi][r] += __shfl_xor(rs[mi][r], off);
#pragma unroll
    for (int mi = 0; mi < 2; ++mi)
#pragma unroll
      for (int r = 0; r < 4; ++r)
        l_r[mi][r] = l_r[mi][r] * alpha[mi][r] + rs[mi][r];
    // rescale O
#pragma unroll
    for (int mi = 0; mi < 2; ++mi)
#pragma unroll
      for (int nd = 0; nd < 4; ++nd)
#pragma unroll
        for (int r = 0; r < 4; ++r) oacc[mi][nd][r] *= alpha[mi][r];
    // P -> per-wave LDS (transpose acc layout -> row-major [q_local][key])
#pragma unroll
    for (int mi = 0; mi < 2; ++mi)
#pragma unroll
      for (int ni = 0; ni < 4; ++ni)
#pragma unroll
        for (int r = 0; r < 4; ++r)
          Pw[(mi * 16 + l4 * 4 + r) * 72 + ni * 16 + l15] = f2bf(s[mi][ni][r]);

    // O += P V
#pragma unroll
    for (int kk2 = 0; kk2 < 2; ++kk2) {
      s16x8 pa[2], vb[4];
#pragma unroll
      for (int mi = 0; mi < 2; ++mi)
        pa[mi] = *reinterpret_cast<const s16x8*>(
            Pw + (mi * 16 + l15) * 72 + kk2 * 32 + l4 * 8);
#pragma unroll
      for (int nd = 0; nd < 4; ++nd)
        vb[nd] = *reinterpret_cast<const s16x8*>(
            Vt + (nd * 16 + l15) * 72 + kk2 * 32 + l4 * 8);
#pragma unroll
      for (int mi = 0; mi < 2; ++mi)
#pragma unroll
        for (int nd = 0; nd < 4; ++nd)
          oacc[mi][nd] = mfma16(pa[mi], vb[nd], oacc[mi][nd]);
    }
    __syncthreads();
  }

#pragma unroll
  for (int mi = 0; mi < 2; ++mi)
#pragma unroll
    for (int r = 0; r < 4; ++r) {
      const float inv = 1.0f / l_r[mi][r];
      const int q = q0 + mi * 16 + l4 * 4 + r;
#pragma unroll
      for (int nd = 0; nd < 4; ++nd)
        O[(size_t)(b * 2048 + q) * 1024 + h * 64 + nd * 16 + l15] =
            f2bf(oacc[mi][nd][r] * inv);
    }
}

extern "C" void kernel_launch(void* const* d_in, const int* in_sizes, int n_in,
                              void* d_out, int out_size, void* d_ws,
                              size_t ws_size, hipStream_t stream) {
  const float* qkv   = (const float*)d_in[0];
  const float* in_w  = (const float*)d_in[1];
  const float* in_b  = (const float*)d_in[2];
  const float* out_w = (const float*)d_in[3];
  const float* out_b = (const float*)d_in[4];
  float* out = (float*)d_out;
  char* ws = (char*)d_ws;

  unsigned short* qkv_bf  = (unsigned short*)(ws);                // 16,777,216 B
  unsigned short* win_bf  = (unsigned short*)(ws + 16777216);     //  6,291,456 B
  unsigned short* wout_bf = (unsigned short*)(ws + 23068672);     //  2,097,152 B
  unsigned short* x1      = (unsigned short*)(ws + 25165824);     // 50,331,648 B
  unsigned short* attn_out = qkv_bf;  // reuse (qkv_bf dead after gemm1)

  cvt_f32_bf16<<<2048, 256, 0, stream>>>(qkv, qkv_bf, 8388608, 0);
  cvt_f32_bf16<<<1024, 256, 0, stream>>>(in_w, win_bf, 3145728, 1048576);
  cvt_f32_bf16<<<512, 256, 0, stream>>>(out_w, wout_bf, 1048576, 0);

  gemm_nt<true><<<dim3(24, 64), 256, 0, stream>>>(
      qkv_bf, win_bf, in_b, (void*)x1, 8192, 3072, 1024, 1024);

  attn_fwd<<<dim3(16, 64), 256, 0, stream>>>(x1, attn_out);

  gemm_nt<false><<<dim3(8, 64), 256, 0, stream>>>(
      attn_out, wout_bf, out_b, (void*)out, 8192, 1024, 1024, 0);
}

// Round 2
// 227.433 us; speedup vs baseline: 1.5910x; 1.5910x over previous
//
#include <hip/hip_runtime.h>

// B=4, S=2048, E=1024, H=16, D=64.  M = B*S = 8192.
// Pipeline: cvt(fp32->bf16, Q-part of W_in/b_in pre-scaled by 0.125*log2e)
//   -> gemm1 (x1 = qkv@W_in^T + b_in, bf16) -> flash attn (swapped-QK^T 32x32
//   MFMA, in-register softmax, exp2) -> gemm2 (f32 out).
// Workspace: [0,16MB) qkv_bf (reused as attn_out) | [16MB,+6MB) w_in bf |
//            [+2MB) w_out bf | [24MB, +48MB) x1 bf16 [8192][3072]

typedef __attribute__((ext_vector_type(8))) short s16x8;
typedef __attribute__((ext_vector_type(8))) __bf16 bf16x8;
typedef __attribute__((ext_vector_type(4))) float f32x4;
typedef __attribute__((ext_vector_type(16))) float f32x16;
typedef __attribute__((ext_vector_type(4))) unsigned short u16x4;
typedef __attribute__((ext_vector_type(4))) unsigned int u32x4;

#define QSCALE_F 0.18033688011112042f  /* 0.125 * log2(e) */

#if __has_builtin(__builtin_amdgcn_exp2f)
#define EXP2F(x) __builtin_amdgcn_exp2f(x)
#else
#define EXP2F(x) exp2f(x)
#endif

__device__ __forceinline__ unsigned short f2bf(float f) {
  unsigned int u = __builtin_bit_cast(unsigned int, f);
  u += 0x7fffu + ((u >> 16) & 1u);
  return (unsigned short)(u >> 16);
}

__device__ __forceinline__ f32x4 mfma16(s16x8 a, s16x8 b, f32x4 c) {
  return __builtin_amdgcn_mfma_f32_16x16x32_bf16(
      __builtin_bit_cast(bf16x8, a), __builtin_bit_cast(bf16x8, b), c, 0, 0, 0);
}
__device__ __forceinline__ f32x16 mfma32(s16x8 a, s16x8 b, f32x16 c) {
  return __builtin_amdgcn_mfma_f32_32x32x16_bf16(
      __builtin_bit_cast(bf16x8, a), __builtin_bit_cast(bf16x8, b), c, 0, 0, 0);
}

__device__ __forceinline__ unsigned cvtpk(float lo, float hi) {
  unsigned r;
  asm("v_cvt_pk_bf16_f32 %0, %1, %2" : "=v"(r) : "v"(lo), "v"(hi));
  return r;
}
// new a = {a.lo32, b.lo32}; new b = {a.hi32, b.hi32}
__device__ __forceinline__ void p32swap(unsigned &a, unsigned &b) {
  asm volatile("v_permlane32_swap_b32 %0, %1" : "+v"(a), "+v"(b));
}

#define GLL16(gp, lp) __builtin_amdgcn_global_load_lds(                       \
    (const __attribute__((address_space(1))) void*)(gp),                      \
    (__attribute__((address_space(3))) void*)(lp), 16, 0, 0)

// ---------------- fp32 -> bf16 conversion (first scale_n elems *QSCALE) ----
__global__ void cvt_f32_bf16(const float* __restrict__ in,
                             unsigned short* __restrict__ out,
                             int n, int scale_n) {
  int idx = (blockIdx.x * 256 + threadIdx.x) * 4;
  int stride = gridDim.x * 256 * 4;
  for (int i = idx; i < n; i += stride) {
    const float4 v = *reinterpret_cast<const float4*>(in + i);
    const float sc = (i < scale_n) ? QSCALE_F : 1.0f;
    u16x4 r;
    r.x = f2bf(v.x * sc); r.y = f2bf(v.y * sc);
    r.z = f2bf(v.z * sc); r.w = f2bf(v.w * sc);
    *reinterpret_cast<u16x4*>(out + i) = r;
  }
}

// ---------------- bf16 NT GEMM: C[M,N] = A[M,K] * B[N,K]^T + bias ----------
template <bool OUT_BF16>
__global__ __launch_bounds__(256, 2) void gemm_nt(
    const unsigned short* __restrict__ A, const unsigned short* __restrict__ B,
    const float* __restrict__ bias, void* __restrict__ Cout,
    int M, int N, int K, int qscale_cols) {
  __shared__ __align__(16) unsigned short As[128 * 64];
  __shared__ __align__(16) unsigned short Bs[128 * 64];
  const int tid = threadIdx.x;
  const int lane = tid & 63, w = tid >> 6;
  const int l15 = lane & 15, l4 = lane >> 4;
  const int wr = w >> 1, wc = w & 1;
  const int bm = blockIdx.y * 128, bn = blockIdx.x * 128;

  f32x4 acc[4][4];
#pragma unroll
  for (int i = 0; i < 4; ++i)
#pragma unroll
    for (int j = 0; j < 4; ++j) acc[i][j] = (f32x4){0.f, 0.f, 0.f, 0.f};

  for (int kt = 0; kt < K; kt += 64) {
#pragma unroll
    for (int j = 0; j < 4; ++j) {
      const int gb = (j * 4 + w) * 64;
      const int g = gb + lane;
      const int row = g >> 3, seg = g & 7;
      GLL16(A + (size_t)(bm + row) * K + kt + seg * 8, As + gb * 8);
      GLL16(B + (size_t)(bn + row) * K + kt + seg * 8, Bs + gb * 8);
    }
    __syncthreads();
#pragma unroll
    for (int kk = 0; kk < 2; ++kk) {
      s16x8 a[4], b[4];
#pragma unroll
      for (int mi = 0; mi < 4; ++mi)
        a[mi] = *reinterpret_cast<const s16x8*>(
            As + (wr * 64 + mi * 16 + l15) * 64 + kk * 32 + l4 * 8);
#pragma unroll
      for (int ni = 0; ni < 4; ++ni)
        b[ni] = *reinterpret_cast<const s16x8*>(
            Bs + (wc * 64 + ni * 16 + l15) * 64 + kk * 32 + l4 * 8);
#pragma unroll
      for (int mi = 0; mi < 4; ++mi)
#pragma unroll
        for (int ni = 0; ni < 4; ++ni)
          acc[mi][ni] = mfma16(a[mi], b[ni], acc[mi][ni]);
    }
    __syncthreads();
  }
#pragma unroll
  for (int mi = 0; mi < 4; ++mi) {
#pragma unroll
    for (int ni = 0; ni < 4; ++ni) {
      const int col = bn + wc * 64 + ni * 16 + l15;
      const float bsc = (col < qscale_cols) ? QSCALE_F : 1.0f;
      const float bv = bias[col] * bsc;
#pragma unroll
      for (int r = 0; r < 4; ++r) {
        const int row = bm + wr * 64 + mi * 16 + l4 * 4 + r;
        const float val = acc[mi][ni][r] + bv;
        if (OUT_BF16)
          ((unsigned short*)Cout)[(size_t)row * N + col] = f2bf(val);
        else
          ((float*)Cout)[(size_t)row * N + col] = val;
      }
    }
  }
}

// ---------------- flash attention, swapped-QK^T 32x32 ----------------------
// grid (16 q-tiles of 128, 64 b*h); block 256 = 4 waves, 32 queries/wave.
// S^T = mfma(A=K, B=Q): lane owns query l31; S rows (keys) in regs.
// P -> bf16 A-frags via cvt_pk + permlane32_swap; PV: O[q][d] = P·V with
// B=V[key][d] read from XOR-swizzled Vt[d][key].
__global__ __launch_bounds__(256, 2) void attn_fwd(
    const unsigned short* __restrict__ X1, unsigned short* __restrict__ O) {
  __shared__ __align__(16) unsigned short Ks[64 * 64];  // [key][dk], XOR-swz
  __shared__ __align__(16) unsigned short Vt[64 * 64];  // [d][key],  XOR-swz

  const int qt = blockIdx.x;   // 0..15
  const int bh = blockIdx.y;   // 0..63
  const int b = bh >> 4, h = bh & 15;
  const int tid = threadIdx.x;
  const int lane = tid & 63, w = tid >> 6;
  const int l31 = lane & 31, hi = lane >> 5;

  const unsigned short* Qp = X1 + (size_t)b * 2048 * 3072 + h * 64;
  const unsigned short* Kp = Qp + 1024;
  const unsigned short* Vp = Qp + 2048;
  const int q0 = qt * 128 + w * 32;

  // Q B-fragments (query = l31, dk = kk*16 + hi*8 + e), loaded once.
  s16x8 qf[4];
#pragma unroll
  for (int kk = 0; kk < 4; ++kk)
    qf[kk] = *reinterpret_cast<const s16x8*>(
        Qp + (size_t)(q0 + l31) * 3072 + kk * 16 + hi * 8);

  f32x16 oacc[2];
#pragma unroll
  for (int db = 0; db < 2; ++db)
#pragma unroll
    for (int i = 0; i < 16; ++i) oacc[db][i] = 0.f;
  float m_r = -1e30f, l_r = 0.f;

  for (int kt = 0; kt < 2048; kt += 64) {
    // ---- stage K (swizzled via pre-swizzled global source) ----
#pragma unroll
    for (int j = 0; j < 2; ++j) {
      const int chunk = (j * 4 + w) * 1024;            // wave-uniform
      const int o = chunk + lane * 16;
      const int row = o >> 7;
      const int srcb = (o & 127) ^ ((row & 7) << 4);
      GLL16(Kp + (size_t)(kt + row) * 3072 + (srcb >> 1), (char*)Ks + chunk);
    }
    // ---- stage V transposed + swizzled (reg-staged) ----
#pragma unroll
    for (int j = 0; j < 2; ++j) {
      const int seg = w + 4 * j;  // d-group 0..7
      s16x8 v = *reinterpret_cast<const s16x8*>(
          Vp + (size_t)(kt + lane) * 3072 + seg * 8);
#pragma unroll
      for (int e = 0; e < 8; ++e) {
        const int d = seg * 8 + e;
        const int byt = (d * 128 + lane * 2) ^ ((d & 7) << 4);
        *(unsigned short*)((char*)Vt + byt) = (unsigned short)v[e];
      }
    }
    __syncthreads();

    // ---- S^T = K · Q^T  (8 mfma) ----
    f32x16 sa[2];
#pragma unroll
    for (int sub = 0; sub < 2; ++sub)
#pragma unroll
      for (int i = 0; i < 16; ++i) sa[sub][i] = 0.f;
    __builtin_amdgcn_s_setprio(1);
#pragma unroll
    for (int sub = 0; sub < 2; ++sub) {
      const int row = sub * 32 + l31;
#pragma unroll
      for (int kk = 0; kk < 4; ++kk) {
        const int byt = (row * 128 + kk * 32 + hi * 16) ^ ((row & 7) << 4);
        s16x8 ka = *reinterpret_cast<const s16x8*>((const char*)Ks + byt);
        sa[sub] = mfma32(ka, qf[kk], sa[sub]);
      }
    }
    __builtin_amdgcn_s_setprio(0);

    // ---- in-register online softmax (lane owns query l31) ----
    float m0 = sa[0][0], m1 = sa[0][1], m2 = sa[0][2], m3 = sa[0][3];
#pragma unroll
    for (int i = 4; i < 16; i += 4) {
      m0 = fmaxf(m0, sa[0][i]);     m1 = fmaxf(m1, sa[0][i + 1]);
      m2 = fmaxf(m2, sa[0][i + 2]); m3 = fmaxf(m3, sa[0][i + 3]);
    }
#pragma unroll
    for (int i = 0; i < 16; i += 4) {
      m0 = fmaxf(m0, sa[1][i]);     m1 = fmaxf(m1, sa[1][i + 1]);
      m2 = fmaxf(m2, sa[1][i + 2]); m3 = fmaxf(m3, sa[1][i + 3]);
    }
    float mx = fmaxf(fmaxf(m0, m1), fmaxf(m2, m3));
    mx = fmaxf(mx, __shfl_xor(mx, 32));

    // defer-max (T13): rescale only when tile max grew past THR=8
    if (__any(mx > m_r + 8.0f)) {
      const float mnew = fmaxf(m_r, mx);
      const float alpha = EXP2F(m_r - mnew);
      m_r = mnew;
      l_r *= alpha;
#pragma unroll
      for (int r = 0; r < 16; ++r) {
        const float ar = __shfl(alpha, (r & 3) + 8 * (r >> 2) + 4 * hi);
        oacc[0][r] *= ar;
        oacc[1][r] *= ar;
      }
    }

    // p = exp2(s - m), row-sum
    float s0 = 0.f, s1 = 0.f, s2 = 0.f, s3 = 0.f;
#pragma unroll
    for (int sub = 0; sub < 2; ++sub)
#pragma unroll
      for (int i = 0; i < 16; i += 4) {
        sa[sub][i]     = EXP2F(sa[sub][i] - m_r);     s0 += sa[sub][i];
        sa[sub][i + 1] = EXP2F(sa[sub][i + 1] - m_r); s1 += sa[sub][i + 1];
        sa[sub][i + 2] = EXP2F(sa[sub][i + 2] - m_r); s2 += sa[sub][i + 2];
        sa[sub][i + 3] = EXP2F(sa[sub][i + 3] - m_r); s3 += sa[sub][i + 3];
      }
    float rsum = (s0 + s1) + (s2 + s3);
    rsum += __shfl_xor(rsum, 32);
    l_r += rsum;

    // ---- pack P -> bf16 A-fragments (cvt_pk + permlane32_swap) ----
    s16x8 pa[2][2];
#pragma unroll
    for (int sub = 0; sub < 2; ++sub)
#pragma unroll
      for (int g = 0; g < 2; ++g) {
        unsigned c0 = cvtpk(sa[sub][g * 8 + 0], sa[sub][g * 8 + 1]);
        unsigned c1 = cvtpk(sa[sub][g * 8 + 2], sa[sub][g * 8 + 3]);
        unsigned c2 = cvtpk(sa[sub][g * 8 + 4], sa[sub][g * 8 + 5]);
        unsigned c3 = cvtpk(sa[sub][g * 8 + 6], sa[sub][g * 8 + 7]);
        p32swap(c0, c2);
        p32swap(c1, c3);
        u32x4 t = {c0, c1, c2, c3};
        pa[sub][g] = __builtin_bit_cast(s16x8, t);
      }

    // ---- O += P · V  (8 mfma) ----
    __builtin_amdgcn_s_setprio(1);
#pragma unroll
    for (int db = 0; db < 2; ++db) {
      const int row = db * 32 + l31;
#pragma unroll
      for (int sub = 0; sub < 2; ++sub)
#pragma unroll
        for (int g = 0; g < 2; ++g) {
          const int byt =
              (row * 128 + (sub * 2 + g) * 32 + hi * 16) ^ ((row & 7) << 4);
          s16x8 vb = *reinterpret_cast<const s16x8*>((const char*)Vt + byt);
          oacc[db] = mfma32(pa[sub][g], vb, oacc[db]);
        }
    }
    __builtin_amdgcn_s_setprio(0);
    __syncthreads();
  }

  // ---- epilogue: normalize + store ----
  const float invl = 1.0f / l_r;
#pragma unroll
  for (int r = 0; r < 16; ++r) {
    const int crow = (r & 3) + 8 * (r >> 2) + 4 * hi;
    const float ir = __shfl(invl, crow);
    const size_t base = (size_t)(b * 2048 + q0 + crow) * 1024 + h * 64 + l31;
    O[base] = f2bf(oacc[0][r] * ir);
    O[base + 32] = f2bf(oacc[1][r] * ir);
  }
}

extern "C" void kernel_launch(void* const* d_in, const int* in_sizes, int n_in,
                              void* d_out, int out_size, void* d_ws,
                              size_t ws_size, hipStream_t stream) {
  const float* qkv   = (const float*)d_in[0];
  const float* in_w  = (const float*)d_in[1];
  const float* in_b  = (const float*)d_in[2];
  const float* out_w = (const float*)d_in[3];
  const float* out_b = (const float*)d_in[4];
  float* out = (float*)d_out;
  char* ws = (char*)d_ws;

  unsigned short* qkv_bf  = (unsigned short*)(ws);
  unsigned short* win_bf  = (unsigned short*)(ws + 16777216);
  unsigned short* wout_bf = (unsigned short*)(ws + 23068672);
  unsigned short* x1      = (unsigned short*)(ws + 25165824);
  unsigned short* attn_out = qkv_bf;  // reuse

  cvt_f32_bf16<<<2048, 256, 0, stream>>>(qkv, qkv_bf, 8388608, 0);
  cvt_f32_bf16<<<1024, 256, 0, stream>>>(in_w, win_bf, 3145728, 1048576);
  cvt_f32_bf16<<<512, 256, 0, stream>>>(out_w, wout_bf, 1048576, 0);

  gemm_nt<true><<<dim3(24, 64), 256, 0, stream>>>(
      qkv_bf, win_bf, in_b, (void*)x1, 8192, 3072, 1024, 1024);

  attn_fwd<<<dim3(16, 64), 256, 0, stream>>>(x1, attn_out);

  gemm_nt<false><<<dim3(8, 64), 256, 0, stream>>>(
      attn_out, wout_bf, out_b, (void*)out, 8192, 1024, 1024, 0);
}

// Round 3
// 206.810 us; speedup vs baseline: 1.7496x; 1.0997x over previous
//
#include <hip/hip_runtime.h>

// B=4, S=2048, E=1024, H=16, D=64.  M = B*S = 8192.
// Pipeline: cvt(fp32->bf16, Q-part of W_in/b_in pre-scaled by 0.125*log2e)
//   -> gemm1 (x1 = qkv@W_in^T + b_in, bf16) -> flash attn (swapped-QK^T 32x32
//   MFMA, in-register softmax, exp2, 2-phase double-buffered staging)
//   -> gemm2 (f32 out).
// Workspace: [0,16MB) qkv_bf (reused as attn_out) | [16MB,+6MB) w_in bf |
//            [+2MB) w_out bf | [24MB, +48MB) x1 bf16 [8192][3072]

typedef __attribute__((ext_vector_type(8))) short s16x8;
typedef __attribute__((ext_vector_type(8))) __bf16 bf16x8;
typedef __attribute__((ext_vector_type(4))) float f32x4;
typedef __attribute__((ext_vector_type(16))) float f32x16;
typedef __attribute__((ext_vector_type(4))) unsigned short u16x4;
typedef __attribute__((ext_vector_type(4))) unsigned int u32x4;

#define QSCALE_F 0.18033688011112042f  /* 0.125 * log2(e) */

#if __has_builtin(__builtin_amdgcn_exp2f)
#define EXP2F(x) __builtin_amdgcn_exp2f(x)
#else
#define EXP2F(x) exp2f(x)
#endif

__device__ __forceinline__ unsigned short f2bf(float f) {
  unsigned int u = __builtin_bit_cast(unsigned int, f);
  u += 0x7fffu + ((u >> 16) & 1u);
  return (unsigned short)(u >> 16);
}

__device__ __forceinline__ f32x4 mfma16(s16x8 a, s16x8 b, f32x4 c) {
  return __builtin_amdgcn_mfma_f32_16x16x32_bf16(
      __builtin_bit_cast(bf16x8, a), __builtin_bit_cast(bf16x8, b), c, 0, 0, 0);
}
__device__ __forceinline__ f32x16 mfma32(s16x8 a, s16x8 b, f32x16 c) {
  return __builtin_amdgcn_mfma_f32_32x32x16_bf16(
      __builtin_bit_cast(bf16x8, a), __builtin_bit_cast(bf16x8, b), c, 0, 0, 0);
}

__device__ __forceinline__ unsigned cvtpk(float lo, float hi) {
  unsigned r;
  asm("v_cvt_pk_bf16_f32 %0, %1, %2" : "=v"(r) : "v"(lo), "v"(hi));
  return r;
}
__device__ __forceinline__ void p32swap(unsigned &a, unsigned &b) {
  asm volatile("v_permlane32_swap_b32 %0, %1" : "+v"(a), "+v"(b));
}

#define GLL16(gp, lp) __builtin_amdgcn_global_load_lds(                       \
    (const __attribute__((address_space(1))) void*)(gp),                      \
    (__attribute__((address_space(3))) void*)(lp), 16, 0, 0)

// ---------------- fp32 -> bf16 conversion (first scale_n elems *QSCALE) ----
__global__ void cvt_f32_bf16(const float* __restrict__ in,
                             unsigned short* __restrict__ out,
                             int n, int scale_n) {
  int idx = (blockIdx.x * 256 + threadIdx.x) * 4;
  int stride = gridDim.x * 256 * 4;
  for (int i = idx; i < n; i += stride) {
    const float4 v = *reinterpret_cast<const float4*>(in + i);
    const float sc = (i < scale_n) ? QSCALE_F : 1.0f;
    u16x4 r;
    r.x = f2bf(v.x * sc); r.y = f2bf(v.y * sc);
    r.z = f2bf(v.z * sc); r.w = f2bf(v.w * sc);
    *reinterpret_cast<u16x4*>(out + i) = r;
  }
}

// ---------------- bf16 NT GEMM: C[M,N] = A[M,K] * B[N,K]^T + bias ----------
template <bool OUT_BF16>
__global__ __launch_bounds__(256, 2) void gemm_nt(
    const unsigned short* __restrict__ A, const unsigned short* __restrict__ B,
    const float* __restrict__ bias, void* __restrict__ Cout,
    int M, int N, int K, int qscale_cols) {
  __shared__ __align__(16) unsigned short As[128 * 64];
  __shared__ __align__(16) unsigned short Bs[128 * 64];
  const int tid = threadIdx.x;
  const int lane = tid & 63, w = tid >> 6;
  const int l15 = lane & 15, l4 = lane >> 4;
  const int wr = w >> 1, wc = w & 1;
  const int bm = blockIdx.y * 128, bn = blockIdx.x * 128;

  f32x4 acc[4][4];
#pragma unroll
  for (int i = 0; i < 4; ++i)
#pragma unroll
    for (int j = 0; j < 4; ++j) acc[i][j] = (f32x4){0.f, 0.f, 0.f, 0.f};

  for (int kt = 0; kt < K; kt += 64) {
#pragma unroll
    for (int j = 0; j < 4; ++j) {
      const int gb = (j * 4 + w) * 64;
      const int g = gb + lane;
      const int row = g >> 3, seg = g & 7;
      GLL16(A + (size_t)(bm + row) * K + kt + seg * 8, As + gb * 8);
      GLL16(B + (size_t)(bn + row) * K + kt + seg * 8, Bs + gb * 8);
    }
    __syncthreads();
#pragma unroll
    for (int kk = 0; kk < 2; ++kk) {
      s16x8 a[4], b[4];
#pragma unroll
      for (int mi = 0; mi < 4; ++mi)
        a[mi] = *reinterpret_cast<const s16x8*>(
            As + (wr * 64 + mi * 16 + l15) * 64 + kk * 32 + l4 * 8);
#pragma unroll
      for (int ni = 0; ni < 4; ++ni)
        b[ni] = *reinterpret_cast<const s16x8*>(
            Bs + (wc * 64 + ni * 16 + l15) * 64 + kk * 32 + l4 * 8);
#pragma unroll
      for (int mi = 0; mi < 4; ++mi)
#pragma unroll
        for (int ni = 0; ni < 4; ++ni)
          acc[mi][ni] = mfma16(a[mi], b[ni], acc[mi][ni]);
    }
    __syncthreads();
  }
#pragma unroll
  for (int mi = 0; mi < 4; ++mi) {
#pragma unroll
    for (int ni = 0; ni < 4; ++ni) {
      const int col = bn + wc * 64 + ni * 16 + l15;
      const float bsc = (col < qscale_cols) ? QSCALE_F : 1.0f;
      const float bv = bias[col] * bsc;
#pragma unroll
      for (int r = 0; r < 4; ++r) {
        const int row = bm + wr * 64 + mi * 16 + l4 * 4 + r;
        const float val = acc[mi][ni][r] + bv;
        if (OUT_BF16)
          ((unsigned short*)Cout)[(size_t)row * N + col] = f2bf(val);
        else
          ((float*)Cout)[(size_t)row * N + col] = val;
      }
    }
  }
}

// ---------------- flash attention, swapped-QK^T 32x32, 2-phase pipeline ----
// 1-D grid 1024, XCD-remapped so all 16 q-tiles of a (b,h) share one XCD.
// block 256 = 4 waves, 32 queries/wave. Lane owns query l31 after swapped
// QK^T; softmax fully in-register; P packed via cvt_pk + permlane32_swap.
__global__ __launch_bounds__(256, 4) void attn_fwd(
    const unsigned short* __restrict__ X1, unsigned short* __restrict__ O) {
  __shared__ __align__(16) unsigned short Ks[2][64 * 64];  // [key][dk] XOR-swz
  __shared__ __align__(16) unsigned short Vt[2][64 * 64];  // [d][key]  XOR-swz

  // XCD-aware decode: id%8 = XCD; 8 consecutive bh per XCD; qt outer.
  const int id = blockIdx.x;           // 0..1023
  const int xc = id & 7, r0 = id >> 3;
  const int bh = xc * 8 + (r0 & 7);
  const int qt = r0 >> 3;              // 0..15
  const int b = bh >> 4, h = bh & 15;
  const int tid = threadIdx.x;
  const int lane = tid & 63, w = tid >> 6;
  const int l31 = lane & 31, hi = lane >> 5;

  const unsigned short* Qp = X1 + (size_t)b * 2048 * 3072 + h * 64;
  const unsigned short* Kp = Qp + 1024;
  const unsigned short* Vp = Qp + 2048;
  const int q0 = qt * 128 + w * 32;

  // Q B-fragments (query = l31, dk = kk*16 + hi*8 + e), loaded once.
  s16x8 qf[4];
#pragma unroll
  for (int kk = 0; kk < 4; ++kk)
    qf[kk] = *reinterpret_cast<const s16x8*>(
        Qp + (size_t)(q0 + l31) * 3072 + kk * 16 + hi * 8);

  f32x16 oacc[2];
#pragma unroll
  for (int db = 0; db < 2; ++db)
#pragma unroll
    for (int i = 0; i < 16; ++i) oacc[db][i] = 0.f;
  float m_r = -1e30f, l_r = 0.f;

  // ---- staging helpers ----
  // K: global_load_lds, linear LDS dest, pre-swizzled global source.
  // V: reg-staged (issue-early), transposed+swizzled ds_write (write-late).
  const int vchunk0 = (w) * 1024, vchunk1 = (w + 4) * 1024;  // byte chunks
#define STAGE_K(kt_, buf_)                                                    \
  {                                                                           \
    _Pragma("unroll") for (int j = 0; j < 2; ++j) {                           \
      const int chunk = (j * 4 + w) * 1024;                                   \
      const int o = chunk + lane * 16;                                        \
      const int row = o >> 7;                                                 \
      const int srcb = (o & 127) ^ ((row & 7) << 4);                          \
      GLL16(Kp + (size_t)((kt_) + row) * 3072 + (srcb >> 1),                  \
            (char*)Ks[buf_] + chunk);                                         \
    }                                                                         \
  }
#define LOAD_V(kt_, vr_)                                                      \
  {                                                                           \
    _Pragma("unroll") for (int j = 0; j < 2; ++j) {                           \
      const int seg = w + 4 * j;                                              \
      vr_[j] = *reinterpret_cast<const s16x8*>(                               \
          Vp + (size_t)((kt_) + lane) * 3072 + seg * 8);                      \
    }                                                                         \
  }
#define WRITE_V(vr_, buf_)                                                    \
  {                                                                           \
    _Pragma("unroll") for (int j = 0; j < 2; ++j) {                           \
      const int seg = w + 4 * j;                                              \
      _Pragma("unroll") for (int e = 0; e < 8; ++e) {                         \
        const int d = seg * 8 + e;                                            \
        const int byt = d * 128 + ((lane * 2) ^ (e << 4));                    \
        *(unsigned short*)((char*)Vt[buf_] + byt) = (unsigned short)vr_[j][e];\
      }                                                                       \
    }                                                                         \
  }

  s16x8 vnxt[2];
  // prologue: stage tile 0 into buffer 0
  LOAD_V(0, vnxt);
  STAGE_K(0, 0);
  WRITE_V(vnxt, 0);
  __syncthreads();

  for (int t = 0; t < 32; ++t) {
    const int cur = t & 1;
    const unsigned short* Ksc = Ks[cur];
    const unsigned short* Vtc = Vt[cur];
    // issue next tile's loads before compute (latency hides under compute)
    if (t < 31) {
      LOAD_V((t + 1) * 64, vnxt);
      STAGE_K((t + 1) * 64, cur ^ 1);
    }

    // ---- S^T = K . Q^T  (8 mfma) ----
    f32x16 sa[2];
#pragma unroll
    for (int sub = 0; sub < 2; ++sub)
#pragma unroll
      for (int i = 0; i < 16; ++i) sa[sub][i] = 0.f;
    __builtin_amdgcn_s_setprio(1);
#pragma unroll
    for (int sub = 0; sub < 2; ++sub) {
      const int row = sub * 32 + l31;
#pragma unroll
      for (int kk = 0; kk < 4; ++kk) {
        const int byt = row * 128 + ((kk * 32 + hi * 16) ^ ((l31 & 7) << 4));
        s16x8 ka = *reinterpret_cast<const s16x8*>((const char*)Ksc + byt);
        sa[sub] = mfma32(ka, qf[kk], sa[sub]);
      }
    }
    __builtin_amdgcn_s_setprio(0);

    // ---- in-register online softmax (lane owns query l31) ----
    float m0 = sa[0][0], m1 = sa[0][1], m2 = sa[0][2], m3 = sa[0][3];
#pragma unroll
    for (int i = 4; i < 16; i += 4) {
      m0 = fmaxf(m0, sa[0][i]);     m1 = fmaxf(m1, sa[0][i + 1]);
      m2 = fmaxf(m2, sa[0][i + 2]); m3 = fmaxf(m3, sa[0][i + 3]);
    }
#pragma unroll
    for (int i = 0; i < 16; i += 4) {
      m0 = fmaxf(m0, sa[1][i]);     m1 = fmaxf(m1, sa[1][i + 1]);
      m2 = fmaxf(m2, sa[1][i + 2]); m3 = fmaxf(m3, sa[1][i + 3]);
    }
    float mx = fmaxf(fmaxf(m0, m1), fmaxf(m2, m3));
    mx = fmaxf(mx, __shfl_xor(mx, 32));

    // defer-max (T13): rescale only when tile max grew past THR=8
    if (__any(mx > m_r + 8.0f)) {
      const float mnew = fmaxf(m_r, mx);
      const float alpha = EXP2F(m_r - mnew);
      m_r = mnew;
      l_r *= alpha;
#pragma unroll
      for (int r = 0; r < 16; ++r) {
        const float ar = __shfl(alpha, (r & 3) + 8 * (r >> 2) + 4 * hi);
        oacc[0][r] *= ar;
        oacc[1][r] *= ar;
      }
    }

    // p = exp2(s - m), row-sum
    float s0 = 0.f, s1 = 0.f, s2 = 0.f, s3 = 0.f;
#pragma unroll
    for (int sub = 0; sub < 2; ++sub)
#pragma unroll
      for (int i = 0; i < 16; i += 4) {
        sa[sub][i]     = EXP2F(sa[sub][i] - m_r);     s0 += sa[sub][i];
        sa[sub][i + 1] = EXP2F(sa[sub][i + 1] - m_r); s1 += sa[sub][i + 1];
        sa[sub][i + 2] = EXP2F(sa[sub][i + 2] - m_r); s2 += sa[sub][i + 2];
        sa[sub][i + 3] = EXP2F(sa[sub][i + 3] - m_r); s3 += sa[sub][i + 3];
      }
    float rsum = (s0 + s1) + (s2 + s3);
    rsum += __shfl_xor(rsum, 32);
    l_r += rsum;

    // ---- pack P -> bf16 A-fragments (cvt_pk + permlane32_swap) ----
    s16x8 pa[2][2];
#pragma unroll
    for (int sub = 0; sub < 2; ++sub)
#pragma unroll
      for (int g = 0; g < 2; ++g) {
        unsigned c0 = cvtpk(sa[sub][g * 8 + 0], sa[sub][g * 8 + 1]);
        unsigned c1 = cvtpk(sa[sub][g * 8 + 2], sa[sub][g * 8 + 3]);
        unsigned c2 = cvtpk(sa[sub][g * 8 + 4], sa[sub][g * 8 + 5]);
        unsigned c3 = cvtpk(sa[sub][g * 8 + 6], sa[sub][g * 8 + 7]);
        p32swap(c0, c2);
        p32swap(c1, c3);
        u32x4 tt = {c0, c1, c2, c3};
        pa[sub][g] = __builtin_bit_cast(s16x8, tt);
      }

    // ---- O += P . V  (8 mfma) ----
    __builtin_amdgcn_s_setprio(1);
#pragma unroll
    for (int db = 0; db < 2; ++db) {
      const int row = db * 32 + l31;
#pragma unroll
      for (int sub = 0; sub < 2; ++sub)
#pragma unroll
        for (int g = 0; g < 2; ++g) {
          const int byt =
              row * 128 + (((sub * 2 + g) * 32 + hi * 16) ^ ((l31 & 7) << 4));
          s16x8 vb = *reinterpret_cast<const s16x8*>((const char*)Vtc + byt);
          oacc[db] = mfma32(pa[sub][g], vb, oacc[db]);
        }
    }
    __builtin_amdgcn_s_setprio(0);

    // write next V tile late (its global loads have been in flight all tile)
    if (t < 31) WRITE_V(vnxt, cur ^ 1);
    __syncthreads();
  }

  // ---- epilogue: normalize + store ----
  const float invl = 1.0f / l_r;
#pragma unroll
  for (int r = 0; r < 16; ++r) {
    const int crow = (r & 3) + 8 * (r >> 2) + 4 * hi;
    const float ir = __shfl(invl, crow);
    const size_t base = (size_t)(b * 2048 + q0 + crow) * 1024 + h * 64 + l31;
    O[base] = f2bf(oacc[0][r] * ir);
    O[base + 32] = f2bf(oacc[1][r] * ir);
  }
}

extern "C" void kernel_launch(void* const* d_in, const int* in_sizes, int n_in,
                              void* d_out, int out_size, void* d_ws,
                              size_t ws_size, hipStream_t stream) {
  const float* qkv   = (const float*)d_in[0];
  const float* in_w  = (const float*)d_in[1];
  const float* in_b  = (const float*)d_in[2];
  const float* out_w = (const float*)d_in[3];
  const float* out_b = (const float*)d_in[4];
  float* out = (float*)d_out;
  char* ws = (char*)d_ws;

  unsigned short* qkv_bf  = (unsigned short*)(ws);
  unsigned short* win_bf  = (unsigned short*)(ws + 16777216);
  unsigned short* wout_bf = (unsigned short*)(ws + 23068672);
  unsigned short* x1      = (unsigned short*)(ws + 25165824);
  unsigned short* attn_out = qkv_bf;  // reuse

  cvt_f32_bf16<<<2048, 256, 0, stream>>>(qkv, qkv_bf, 8388608, 0);
  cvt_f32_bf16<<<1024, 256, 0, stream>>>(in_w, win_bf, 3145728, 1048576);
  cvt_f32_bf16<<<512, 256, 0, stream>>>(out_w, wout_bf, 1048576, 0);

  gemm_nt<true><<<dim3(24, 64), 256, 0, stream>>>(
      qkv_bf, win_bf, in_b, (void*)x1, 8192, 3072, 1024, 1024);

  attn_fwd<<<1024, 256, 0, stream>>>(x1, attn_out);

  gemm_nt<false><<<dim3(8, 64), 256, 0, stream>>>(
      attn_out, wout_bf, out_b, (void*)out, 8192, 1024, 1024, 0);
}